// Round 8
// baseline (227.402 us; speedup 1.0000x reference)
//
#include <hip/hip_runtime.h>
#include <math.h>

// Problem constants
#define NB 128     // batch
#define NC 128     // channels
#define NN 170     // nodes
#define NT 12      // length
#define NP 192     // padded node count (12 tiles of 16)
#define MP 176     // P row stride (halfs)

// Workspace regions (halfs)
#define EST_SZ ((size_t)NP * NC)            //   24,576 halfs (48 KB)
#define P_SZ   ((size_t)NB * NN * MP)       // 3,829,760 halfs (7.3 MB)

typedef _Float16 h8 __attribute__((ext_vector_type(8)));
typedef float    f4 __attribute__((ext_vector_type(4)));

// tanh via hw exp+rcp: ~6 VALU ops. rel err ~1e-6. Clamp sanitizes inf.
__device__ __forceinline__ float fast_tanh(float x) {
    float cx = fminf(fmaxf(x, -15.f), 15.f);
    float e  = __expf(2.f * cx);
    return (e - 1.f) * __builtin_amdgcn_rcpf(e + 1.f);
}

// ---------------------------------------------------------------------------
// KPREP: Est[m][c] = f16(Es[c][m]) for m<170, rows [170,192) zero (these
// zeros make EdL's pad cols exact zeros downstream). Proven.
// ---------------------------------------------------------------------------
__global__ __launch_bounds__(256) void kprep_est(const float* __restrict__ Es,
                                                 _Float16* __restrict__ Est) {
    int idx = blockIdx.x * 256 + threadIdx.x;       // [0, 192*128)
    int m = idx >> 7, c = idx & 127;
    Est[idx] = (m < NN) ? (_Float16)Es[c * NN + m] : (_Float16)0.f;
}

// ---------------------------------------------------------------------------
// KA — grid (2,128): block (h,b) = half h of batch b, 1024 thr = 16 waves.
// R7 A/B evidence: 128->256 blocks doubled traffic (FETCH 65->131 MB, hbm
// 0.95->1.75 TB/s) at CONSTANT 80us => duration = per-block critical path.
// That path was phase1's barrier cadence: hipcc emits s_waitcnt vmcnt(0)
// before every __syncthreads s_barrier, so all 16 barriers fully drained the
// load queue (zero cross-round overlap).
// THIS ROUND: phase1 re-pipelined -- 16 rounds of 8 channels, LDS dbuf
// Lb[2][4080] (same 32,640B), ONE RAW barrier per round:
//     s_waitcnt lgkmcnt(0); s_barrier; sched_barrier(0)
// (T4: never vmcnt-drain in the loop). Round r+1's 4 float4 loads/thread are
// issued before the barrier and stay IN FLIGHT through round r's reduce.
// Hazard proof (1 barrier + dbuf): iter r+2 writes Lb[cur] only after
// BAR(r+1); every thread reaches BAR(r+1) only after its reduce-r reads of
// Lb[cur] completed (explicit lgkmcnt(0) drains them). Loads cross barriers
// harmlessly (consumed next iteration via compiler vmcnt).
// GEMM1/GEMM2/softmax identical to the R7-proven code (absmax 0).
// LDS: 32,640 (Lb) + 49,152 (At/Sc) + 73,728 (EdL) = 155,520 B -> 1 blk/CU.
// ---------------------------------------------------------------------------
#define ATSW(row, c)  ((row) * 128 + (((((c) >> 3) ^ ((row) & 7)) << 3) | ((c) & 7)))
#define EDSW(row, m)  ((row) * 192 + (((((m) >> 3) ^ ((row) & 7)) << 3) | ((m) & 7)))
#define SCSTR 204

__global__ __launch_bounds__(1024) void kA_fused(const float* __restrict__ x,
                                                 const _Float16* __restrict__ Est,
                                                 _Float16* __restrict__ P) {
    const int h = blockIdx.x, b = blockIdx.y;
    const int r0 = h * 96;                          // this block's output rows
    const int t = threadIdx.x;                      // [0,1024)
    const int lane = t & 63, wave = t >> 6;         // wave [0,16)
    const int l15 = lane & 15, quad = lane >> 4;
    const int wr = wave >> 2, wc = wave & 3;        // 4x4 wave grid (GEMM1)

    __shared__ __align__(16) float    Lb[2 * 4080];      // 32,640 B dbuf t-sum
    __shared__ __align__(16) char     UN[192 * 128 * 2]; // 49,152 B At, later Sc
    __shared__ __align__(16) _Float16 EdL[192 * 192];    // 73,728 B
    _Float16* At = (_Float16*)UN;                   // [192 n][128 c] swizzled
    float*    Sc = (float*)UN;                      // [48][SCSTR] f32 (39,168 B)

    // ---- phase 1: pipelined t-sum. 16 rounds x 8 channels (4080 float4). ----
    const float4* xb = reinterpret_cast<const float4*>(x + (size_t)b * NC * NN * NT);
    float4 vv[4];
    #pragma unroll
    for (int it = 0; it < 4; ++it) {                // prologue: round 0 loads
        int s = t + it * 1024;
        vv[it] = (s < 4080) ? xb[s] : make_float4(0.f, 0.f, 0.f, 0.f);
    }
    for (int r = 0; r < 16; ++r) {
        const int cur = (r & 1) * 4080;
        #pragma unroll
        for (int it = 0; it < 4; ++it) {            // consume vv -> Lb[cur]
            int s = t + it * 1024;
            if (s < 4080)
                Lb[cur + s] = (vv[it].x + vv[it].y) + (vv[it].z + vv[it].w);
        }
        if (r < 15) {                               // issue next round's loads
            const float4* xr = xb + (size_t)(r + 1) * 4080;
            #pragma unroll
            for (int it = 0; it < 4; ++it) {
                int s = t + it * 1024;
                vv[it] = (s < 4080) ? xr[s] : make_float4(0.f, 0.f, 0.f, 0.f);
            }
        }
        // RAW barrier: drain LDS only; prefetched global loads stay in flight.
        asm volatile("s_waitcnt lgkmcnt(0)" ::: "memory");
        __builtin_amdgcn_s_barrier();
        __builtin_amdgcn_sched_barrier(0);
        // reduce 3:1 -> At. 1536 slots = 192n x 8c; lane-groups (8 lanes, same
        // n, cc 0..7) write 16B contiguous; XOR group = r^(n&7) puts the 8
        // n-groups of a wave on disjoint bank quads (conflict-free).
        #pragma unroll
        for (int it = 0; it < 2; ++it) {
            int idx = t + it * 1024;
            if (idx < 1536) {
                int n = idx >> 3, cc = idx & 7;
                float sv = 0.f;
                if (n < NN)
                    sv = Lb[cur + cc * 510 + 3 * n] + Lb[cur + cc * 510 + 3 * n + 1]
                       + Lb[cur + cc * 510 + 3 * n + 2];
                At[ATSW(n, r * 8 + cc)] = (_Float16)sv;  // n>=170 rows exact 0
            }
        }
        // single barrier per round (see hazard proof in header comment)
    }
    __syncthreads();                                // At complete

    // ---- GEMM1: EdL = tanh(At · Est^T), 16 waves, tile 48x48 each ----
    {
        f4 acc1[3][3] = {};
        #pragma unroll
        for (int kk = 0; kk < 4; ++kk) {            // K = 128
            int ks = kk * 32 + quad * 8;
            h8 a[3], bf[3];
            #pragma unroll
            for (int rt = 0; rt < 3; ++rt) {
                int row = wr * 48 + rt * 16 + l15;
                a[rt] = *reinterpret_cast<const h8*>(
                    &At[row * 128 + (((ks >> 3) ^ (row & 7)) << 3)]);
            }
            #pragma unroll
            for (int ci = 0; ci < 3; ++ci) {
                int m = wc * 48 + ci * 16 + l15;
                bf[ci] = *reinterpret_cast<const h8*>(Est + (size_t)m * NC + ks);
            }
            #pragma unroll
            for (int rt = 0; rt < 3; ++rt)
                #pragma unroll
                for (int ci = 0; ci < 3; ++ci)
                    acc1[rt][ci] = __builtin_amdgcn_mfma_f32_16x16x32_f16(
                        a[rt], bf[ci], acc1[rt][ci], 0, 0, 0);
        }
        // epilogue: tanh -> EdL (swizzled b16 writes)
        #pragma unroll
        for (int rt = 0; rt < 3; ++rt)
            #pragma unroll
            for (int ci = 0; ci < 3; ++ci) {
                int m = wc * 48 + ci * 16 + l15;
                #pragma unroll
                for (int reg = 0; reg < 4; ++reg) {
                    int n = wr * 48 + rt * 16 + quad * 4 + reg;
                    EdL[EDSW(n, m)] = (_Float16)fast_tanh(acc1[rt][ci][reg]);
                }
            }
    }
    __syncthreads();                                // EdL complete; At dead

    // ---- GEMM2: this half's 96 rows x 192 cols = 2x4 grid of 48x48 ----
    f4 acc2[3][3] = {};
    if (wave < 8) {
        const int gr = wave >> 2, gc = wave & 3;
        #pragma unroll 2
        for (int mc = 0; mc < 192; mc += 32) {      // K = 192 (pad cols are 0)
            int mg = (mc >> 3) + quad;
            h8 a2[3], b2[3];
            #pragma unroll
            for (int rt = 0; rt < 3; ++rt) {
                int row = r0 + gr * 48 + rt * 16 + l15;
                a2[rt] = *reinterpret_cast<const h8*>(
                    &EdL[row * 192 + ((mg ^ (row & 7)) << 3)]);
            }
            #pragma unroll
            for (int ci = 0; ci < 3; ++ci) {
                int row = gc * 48 + ci * 16 + l15;  // score col base
                b2[ci] = *reinterpret_cast<const h8*>(
                    &EdL[row * 192 + ((mg ^ (row & 7)) << 3)]);
            }
            #pragma unroll
            for (int rt = 0; rt < 3; ++rt)
                #pragma unroll
                for (int ci = 0; ci < 3; ++ci)
                    acc2[rt][ci] = __builtin_amdgcn_mfma_f32_16x16x32_f16(
                        a2[rt], b2[ci], acc2[rt][ci], 0, 0, 0);
        }
    }

    // ---- 2 rounds of 48 rows: scatter (waves gr==p) -> softmax (all) ----
    const float scale = 0.08838834764831845f;       // 1/sqrt(128)
    for (int p = 0; p < 2; ++p) {
        __syncthreads();                            // prev round's Sc reads done
        if (wave < 8 && (wave >> 2) == p) {
            const int gc = wave & 3;
            #pragma unroll
            for (int rt = 0; rt < 3; ++rt)
                #pragma unroll
                for (int ci = 0; ci < 3; ++ci) {
                    int col = gc * 48 + ci * 16 + l15;
                    #pragma unroll
                    for (int reg = 0; reg < 4; ++reg) {
                        int rloc = rt * 16 + quad * 4 + reg;
                        Sc[rloc * SCSTR + col] = fmaxf(acc2[rt][ci][reg] * scale, 0.f);
                    }
                }
        }
        __syncthreads();
        // proven wave-parallel softmax; wave owns 3 rows of this 48-row round
        #pragma unroll
        for (int rr = 0; rr < 3; ++rr) {
            int r = wave * 3 + rr;
            int n = r0 + p * 48 + r;
            if (n >= NN) continue;
            float v0 = Sc[r * SCSTR + lane];
            float v1 = Sc[r * SCSTR + lane + 64];
            int  k2i = lane + 128;
            bool has2 = (k2i < NN);
            float v2 = has2 ? Sc[r * SCSTR + k2i] : -1.f;
            float m = fmaxf(fmaxf(v0, v1), v2);
            #pragma unroll
            for (int off = 32; off; off >>= 1) m = fmaxf(m, __shfl_xor(m, off, 64));
            float e0 = __expf(v0 - m);
            float e1 = __expf(v1 - m);
            float e2 = has2 ? __expf(v2 - m) : 0.f;
            float s = e0 + e1 + e2;
            #pragma unroll
            for (int off = 32; off; off >>= 1) s += __shfl_xor(s, off, 64);
            float inv = 1.f / s;
            _Float16* Pr = P + ((size_t)(b * NN + n)) * MP;
            Pr[lane]      = (_Float16)(e0 * inv);
            Pr[lane + 64] = (_Float16)(e1 * inv);
            if (has2) Pr[k2i] = (_Float16)(e2 * inv);
        }
    }
}

// ---------------------------------------------------------------------------
// K4: mean over batch + threshold in one pass. 8-way accumulator ILP (was
// 4-way) for 2x outstanding loads; otherwise the proven R5 kernel.
// ---------------------------------------------------------------------------
__global__ __launch_bounds__(256) void k4_mean_thresh(const _Float16* __restrict__ P,
                                                      float* __restrict__ out) {
    int p = blockIdx.x * 256 + threadIdx.x;
    if (p >= NN * NN) return;
    int n = p / NN, k = p - n * NN;
    const _Float16* base = P + (size_t)n * MP + k;
    float s0 = 0.f, s1 = 0.f, s2 = 0.f, s3 = 0.f;
    float s4 = 0.f, s5 = 0.f, s6 = 0.f, s7 = 0.f;
    #pragma unroll
    for (int b = 0; b < NB; b += 8) {
        s0 += (float)base[(size_t)(b + 0) * NN * MP];
        s1 += (float)base[(size_t)(b + 1) * NN * MP];
        s2 += (float)base[(size_t)(b + 2) * NN * MP];
        s3 += (float)base[(size_t)(b + 3) * NN * MP];
        s4 += (float)base[(size_t)(b + 4) * NN * MP];
        s5 += (float)base[(size_t)(b + 5) * NN * MP];
        s6 += (float)base[(size_t)(b + 6) * NN * MP];
        s7 += (float)base[(size_t)(b + 7) * NN * MP];
    }
    float s = ((s0 + s1) + (s2 + s3)) + ((s4 + s5) + (s6 + s7));
    out[p] = (s * (1.f / 128.f) > 0.5f) ? 1.f : 0.f;
}

// ---------------------------------------------------------------------------
// Workspace layout (halfs):
//   [0, EST_SZ)   : Est (f16, [192][128])   live through KA
//   [+, +P_SZ)    : P   (f16, [b][n][176])  dead after K4
// Total = 7.4 MB.
// ---------------------------------------------------------------------------
extern "C" void kernel_launch(void* const* d_in, const int* in_sizes, int n_in,
                              void* d_out, int out_size, void* d_ws, size_t ws_size,
                              hipStream_t stream) {
    const float* x  = (const float*)d_in[0];   // [128,128,170,12] f32
    const float* Es = (const float*)d_in[1];   // [128,170] f32
    float* out = (float*)d_out;                // [170,170] f32

    _Float16* Est = (_Float16*)d_ws;
    _Float16* P   = Est + EST_SZ;

    kprep_est<<<96, 256, 0, stream>>>(Es, Est);
    kA_fused<<<dim3(2, 128), 1024, 0, stream>>>(x, Est, P);
    k4_mean_thresh<<<113, 256, 0, stream>>>(P, out);
}